// Round 11
// baseline (88.811 us; speedup 1.0000x reference)
//
#include <hip/hip_runtime.h>
#include <hip/hip_fp16.h>

// KnnExpansion: out[f, n] = sum_k alpha[i[n,k], f] * exp(-0.5 * d[n,k] / sigma^2)
// N=131072, K=32, M=65536, F=64.
//
// Proven structure (r10): fused in-register quartile partition + 4-phase
// L2-resident gather, batched prologue. This round halves L2 line-requests:
// per-row int8 table (64B row = ONE 64B line vs f16's two). The r5 failure
// (scalar s_load scale lookups serializing the hot loop) is fixed by folding
// scale into the packed weight at PREP time: prologue hi lanes vector-gather
// scale[idx] (256KiB L2-hot), pack pk = idx<<16 | f16(w*scale). The consume
// loop keeps r10's exact shape: readlane -> SGPR base, global_load_sbyte,
// cvt, fma. Quant error proven in r4: absmax 0.156 << 0.4875.

#define N_Q    131072
#define K_NB   32
#define F_CH   64
#define M_ROWS 65536

// ---- pre-pass: per-row int8 quantization (one wave per row) ----
__global__ __launch_bounds__(256) void quant_rows(
    const float* __restrict__ alpha,   // [65536, 64]
    signed char* __restrict__ a8,      // [65536, 64]
    float*       __restrict__ scale)   // [65536]
{
    const int lane = threadIdx.x & 63;
    const int row  = (blockIdx.x << 2) + (threadIdx.x >> 6);   // 4 rows/block

    const float v = __builtin_nontemporal_load(&alpha[(size_t)row * F_CH + lane]);
    float m = fabsf(v);
    #pragma unroll
    for (int off = 32; off; off >>= 1) m = fmaxf(m, __shfl_xor(m, off));

    const float inv = (m > 0.0f) ? (127.0f / m) : 0.0f;
    a8[(size_t)row * F_CH + lane] = (signed char)(int)rintf(v * inv);
    if (lane == 0) scale[row] = m * (1.0f / 127.0f);
}

// ---- fused main: batched prologue + quartile partition + 4-phase gather ----
__global__ __launch_bounds__(512) void knn_exp_i8_phased(
    const float*       __restrict__ dmat,   // [N, 32]
    const int*         __restrict__ imat,   // [N, 32]
    const signed char* __restrict__ a8,     // [65536, 64]
    const float*       __restrict__ scale,  // [65536]
    const float*       __restrict__ sigma,  // [1]
    float*             __restrict__ out)    // [64, N]
{
    __shared__ float    tile[64][65];        // +1 pad
    __shared__ unsigned sortbuf[8][8][32];   // wave-local sort scratch

    const int lane = threadIdx.x & 63;
    const int wave = threadIdx.x >> 6;       // 8 waves x 8 queries
    const int n0   = blockIdx.x * 64;
    const bool hi  = (lane >= 32);

    const float s = sigma[0];
    const float c = -0.5f / (s * s);

    // ---- batched prologue: 8 stream loads issued back-to-back ----
    // lo lanes -> d[n][lane], hi lanes -> i[n][lane-32]
    const int nbase = n0 + wave * 8;
    const char* pbase = hi
        ? (const char*)&imat[(size_t)nbase * K_NB + (lane - 32)]
        : (const char*)&dmat[(size_t)nbase * K_NB + lane];
    unsigned raw[8];
    #pragma unroll
    for (int qi = 0; qi < 8; ++qi)
        raw[qi] = __builtin_nontemporal_load(
            (const unsigned*)(pbase + (size_t)qi * (K_NB * 4)));

    __builtin_amdgcn_sched_barrier(0);   // keep the batch; no sinking

    // ---- batched scale gathers: hi lanes fetch scale[idx] (256KiB, L2-hot)
    // index masked to [0,65536) -> always in-bounds, no divergent guard.
    float srow[8];
    #pragma unroll
    for (int qi = 0; qi < 8; ++qi)
        srow[qi] = scale[raw[qi] & 0xFFFFu];

    __builtin_amdgcn_sched_barrier(0);

    // ---- in-register quartile partition, pack (idx<<16 | f16(w*scale)) ----
    #pragma unroll
    for (int qi = 0; qi < 8; ++qi) {
        const float wv = __expf(c * __uint_as_float(raw[qi])); // valid on lo
        const int   iv = (int)raw[qi];                         // valid on hi

        // hi lanes pull partner's w, fold in their row scale, cvt to f16
        const float wp = __shfl(wv, lane & 31);
        const unsigned hb = (unsigned)__half_as_ushort(
            __float2half_rn(wp * srow[qi]));

        const int quart = (iv >> 14) & 3;
        const unsigned long long m0 = __ballot(hi && quart == 0);
        const unsigned long long m1 = __ballot(hi && quart == 1);
        const unsigned long long m2 = __ballot(hi && quart == 2);
        const unsigned long long m3 = __ballot(hi && quart == 3);
        const int b1 = __popcll(m0);
        const int b2 = b1 + __popcll(m1);
        const int b3 = b2 + __popcll(m2);
        const unsigned long long mq =
            (quart == 0) ? m0 : (quart == 1) ? m1 : (quart == 2) ? m2 : m3;
        const int bq =
            (quart == 0) ? 0 : (quart == 1) ? b1 : (quart == 2) ? b2 : b3;
        const unsigned long long below = (1ull << lane) - 1ull;
        const int pos = bq + __popcll(mq & below);

        if (hi)
            sortbuf[wave][qi][pos] = ((unsigned)iv << 16) | (hb & 0xFFFFu);
    }

    // wave-local RAW through LDS (lgkmcnt-ordered, no barrier needed)
    unsigned pv[8];
    float    acc[8];
    #pragma unroll
    for (int qi = 0; qi < 8; ++qi) {
        pv[qi]  = sortbuf[wave][qi][lane & 31];
        acc[qi] = 0.0f;
    }

    // ---- 4-phase consume: phase p ~= quartile p (1 MiB L2 slice).
    // One 64B line per row; weight already carries the row scale.
    #pragma unroll
    for (int p = 0; p < 4; ++p) {
        #pragma unroll
        for (int qi = 0; qi < 8; ++qi) {
            #pragma unroll
            for (int j = 0; j < 8; ++j) {
                const unsigned pk = (unsigned)__builtin_amdgcn_readlane(
                    (int)pv[qi], p * 8 + j);              // SGPR
                __half_raw hr; hr.x = (unsigned short)(pk & 0xFFFFu);
                const float w = __half2float(__half(hr));
                const unsigned off = (pk >> 16) << 6;     // 64B rows
                const signed char q =
                    *(const signed char*)((const char*)a8 + off + lane);
                acc[qi] = fmaf(w, (float)q, acc[qi]);
            }
        }
    }

    #pragma unroll
    for (int qi = 0; qi < 8; ++qi)
        tile[wave * 8 + qi][lane] = acc[qi];

    __syncthreads();

    // coalesced [F, N] store: each wave writes 8 channel-rows of 64 floats
    #pragma unroll
    for (int fi = 0; fi < 8; ++fi) {
        const int f = wave * 8 + fi;
        __builtin_nontemporal_store(tile[lane][f],
                                    &out[(size_t)f * N_Q + n0 + lane]);
    }
}

// ---- fallback: pure fp32 (no workspace) ----
__global__ __launch_bounds__(256) void knn_exp_f32(
    const float* __restrict__ dmat,
    const int*   __restrict__ imat,
    const float* __restrict__ alpha,
    const float* __restrict__ sigma,
    float*       __restrict__ out)
{
    __shared__ float tile[64][65];
    const int lane = threadIdx.x & 63;
    const int wave = threadIdx.x >> 6;
    const int n0   = blockIdx.x * 64;
    const float s = sigma[0];
    const float c = -0.5f / (s * s);

    for (int qi = 0; qi < 16; ++qi) {
        const int q = wave * 16 + qi;
        const int n = n0 + q;
        float wv = 0.0f;
        int   iv = 0;
        if (lane < 32) {
            wv = __expf(c * dmat[(size_t)n * K_NB + lane]);
        } else {
            iv = imat[(size_t)n * K_NB + (lane - 32)];
        }
        float acc = 0.0f;
        #pragma unroll
        for (int k = 0; k < K_NB; ++k) {
            const float wk = __int_as_float(
                __builtin_amdgcn_readlane(__float_as_int(wv), k));
            const int   ik = __builtin_amdgcn_readlane(iv, 32 + k);
            acc = fmaf(wk, alpha[(size_t)ik * F_CH + lane], acc);
        }
        tile[q][lane] = acc;
    }
    __syncthreads();
    #pragma unroll
    for (int fi = 0; fi < 16; ++fi) {
        const int f = wave * 16 + fi;
        out[(size_t)f * N_Q + n0 + lane] = tile[lane][f];
    }
}

extern "C" void kernel_launch(void* const* d_in, const int* in_sizes, int n_in,
                              void* d_out, int out_size, void* d_ws, size_t ws_size,
                              hipStream_t stream) {
    const float* dmat  = (const float*)d_in[0];
    const int*   imat  = (const int*)d_in[1];
    const float* alpha = (const float*)d_in[2];
    const float* sigma = (const float*)d_in[3];
    float* out = (float*)d_out;

    const size_t bytes_a8    = (size_t)M_ROWS * F_CH;            // 4 MiB
    const size_t bytes_scale = (size_t)M_ROWS * sizeof(float);   // 256 KiB

    if (ws_size >= bytes_a8 + bytes_scale) {
        signed char* a8  = (signed char*)d_ws;
        float*       scl = (float*)((char*)d_ws + bytes_a8);
        hipLaunchKernelGGL(quant_rows, dim3(M_ROWS / 4), dim3(256), 0, stream,
                           alpha, a8, scl);
        hipLaunchKernelGGL(knn_exp_i8_phased, dim3(N_Q / 64), dim3(512), 0,
                           stream, dmat, imat, a8, scl, sigma, out);
    } else {
        hipLaunchKernelGGL(knn_exp_f32, dim3(N_Q / 64), dim3(256), 0, stream,
                           dmat, imat, alpha, sigma, out);
    }
}